// Round 1
// baseline (22579.048 us; speedup 1.0000x reference)
//
#include <hip/hip_runtime.h>

#define NITEMS 169

// ---------------------------------------------------------------------------
// conv1 fused with mvol construction:
//   in: fmap1 (32,64,128), fmap2 (32,64,128); item n -> shift (dx,dy)
//   mvol channel c<32 : fmap1[c][y][x]        * inb(y+dy, x+dx)
//   mvol channel c>=32: fmap2[c-32][y+dy][x+dx] (zero outside bounds)
//   out: relu(conv3x3(mvol, w1)) -> (96,64,128) per item
// ---------------------------------------------------------------------------
__global__ __launch_bounds__(256)
void k_conv1(const float* __restrict__ f1, const float* __restrict__ f2,
             const float* __restrict__ w1, float* __restrict__ out, int base) {
  const int g = blockIdx.y;
  const int n = base + g;
  const int dx = (n / 13) - 6;
  const int dy = (n % 13) - 6;
  const int pix = blockIdx.x * 256 + threadIdx.x;   // 0..8191
  const int oy = pix >> 7, ox = pix & 127;
  float* op = out + (size_t)g * (96 * 8192);

  float acc[96];
#pragma unroll
  for (int c = 0; c < 96; ++c) acc[c] = 0.f;

#pragma unroll 1
  for (int ci = 0; ci < 32; ++ci) {
    float pa[9], pb[9];
#pragma unroll
    for (int t = 0; t < 9; ++t) {
      const int yy = oy - 1 + t / 3;
      const int xx = ox - 1 + t % 3;
      const int sy = yy + dy, sx = xx + dx;
      const bool okA = ((unsigned)yy < 64u) && ((unsigned)xx < 128u);
      const bool okS = ((unsigned)sy < 64u) && ((unsigned)sx < 128u);
      const bool ok = okA && okS;
      pa[t] = ok ? f1[(ci * 64 + yy) * 128 + xx] : 0.f;
      pb[t] = ok ? f2[(ci * 64 + sy) * 128 + sx] : 0.f;
    }
#pragma unroll
    for (int co = 0; co < 96; ++co) {
      const float* wa = w1 + (size_t)(co * 64 + ci) * 9;        // fmap1 half
      const float* wb = w1 + (size_t)(co * 64 + ci + 32) * 9;   // fmap2 half
      float s = acc[co];
#pragma unroll
      for (int t = 0; t < 9; ++t) s += pa[t] * wa[t];
#pragma unroll
      for (int t = 0; t < 9; ++t) s += pb[t] * wb[t];
      acc[co] = s;
    }
  }
#pragma unroll
  for (int co = 0; co < 96; ++co)
    op[co * 8192 + pix] = fmaxf(acc[co], 0.f);
}

// ---------------------------------------------------------------------------
// Generic 3x3 conv, pad 1, optional stride 2, optional relu.
// One thread per output pixel; all COUT accumulators in registers;
// weights are wave-uniform scalar loads.
// ---------------------------------------------------------------------------
template <int CIN, int COUT, int STRIDE, bool RELU, int HIN, int WIN>
__global__ __launch_bounds__(256)
void k_conv3x3(const float* __restrict__ in, const float* __restrict__ w,
               float* __restrict__ out) {
  constexpr int HOUT = HIN / STRIDE, WOUT = WIN / STRIDE;
  const int g = blockIdx.y;
  const int pix = blockIdx.x * 256 + threadIdx.x;
  const int oy = pix / WOUT, ox = pix % WOUT;
  const float* ip = in + (size_t)g * (CIN * HIN * WIN);
  float* op = out + (size_t)g * (COUT * HOUT * WOUT);

  float acc[COUT];
#pragma unroll
  for (int c = 0; c < COUT; ++c) acc[c] = 0.f;

  const int iy0 = oy * STRIDE - 1, ix0 = ox * STRIDE - 1;
#pragma unroll 1
  for (int ci = 0; ci < CIN; ++ci) {
    float p[9];
#pragma unroll
    for (int t = 0; t < 9; ++t) {
      const int yy = iy0 + t / 3, xx = ix0 + t % 3;
      const bool ok = ((unsigned)yy < (unsigned)HIN) && ((unsigned)xx < (unsigned)WIN);
      p[t] = ok ? ip[(ci * HIN + yy) * WIN + xx] : 0.f;
    }
#pragma unroll
    for (int co = 0; co < COUT; ++co) {
      const float* wp = w + (size_t)(co * CIN + ci) * 9;
      float s = acc[co];
#pragma unroll
      for (int t = 0; t < 9; ++t) s += p[t] * wp[t];
      acc[co] = s;
    }
  }
#pragma unroll
  for (int co = 0; co < COUT; ++co) {
    float v = acc[co];
    if (RELU) v = fmaxf(v, 0.f);
    op[(co * HOUT + oy) * WOUT + ox] = v;
  }
}

// ---------------------------------------------------------------------------
// ConvTranspose2d(64->32, k=4, s=2, p=1) + relu.
// Expressed as lhs-dilated cross-correlation (matches jax _deconv exactly):
//   out[o][oy][ox] = sum_{i,ky,kx: oy-2+ky=2*iy, ox-2+kx=2*ix} in[i][iy][ix]*wd[o][i][ky][kx]
// Each thread computes a 2x2 output quad so ky/kx are compile-time constants
// (keeps weight loads wave-uniform).
//   in: (64,32,64) -> out: (32,64,128)
// ---------------------------------------------------------------------------
__global__ __launch_bounds__(256)
void k_deconv(const float* __restrict__ in, const float* __restrict__ wd,
              float* __restrict__ out) {
  const int g = blockIdx.y;
  const int q = blockIdx.x * 256 + threadIdx.x;   // 0..2047 quads
  const int m = q >> 6, p = q & 63;               // out rows 2m..2m+1, cols 2p..2p+1
  const float* ip = in + (size_t)g * (64 * 32 * 64);
  float* op = out + (size_t)g * (32 * 8192);

  float acc[2][2][32];
#pragma unroll
  for (int a = 0; a < 2; ++a)
#pragma unroll
    for (int b = 0; b < 2; ++b)
#pragma unroll
      for (int c = 0; c < 32; ++c) acc[a][b][c] = 0.f;

#pragma unroll 1
  for (int ci = 0; ci < 64; ++ci) {
    float pv[3][3];
#pragma unroll
    for (int r = 0; r < 3; ++r)
#pragma unroll
      for (int s = 0; s < 3; ++s) {
        const int iy = m - 1 + r, ix = p - 1 + s;
        const bool ok = ((unsigned)iy < 32u) && ((unsigned)ix < 64u);
        pv[r][s] = ok ? ip[(ci * 32 + iy) * 64 + ix] : 0.f;
      }
#pragma unroll
    for (int a = 0; a < 2; ++a)
#pragma unroll
      for (int b = 0; b < 2; ++b)
#pragma unroll
        for (int u = 0; u < 2; ++u)
#pragma unroll
          for (int v = 0; v < 2; ++v) {
            const int r = (a == 0) ? u : (u + 1);     // input row offset index
            const int s = (b == 0) ? v : (v + 1);
            const int ky = (a == 0) ? (2 * u) : (2 * u + 1);
            const int kx = (b == 0) ? (2 * v) : (2 * v + 1);
            const float x = pv[r][s];
#pragma unroll
            for (int co = 0; co < 32; ++co)
              acc[a][b][co] += x * wd[((size_t)(co * 64 + ci) * 4 + ky) * 4 + kx];
          }
  }
#pragma unroll
  for (int co = 0; co < 32; ++co)
#pragma unroll
    for (int a = 0; a < 2; ++a)
#pragma unroll
      for (int b = 0; b < 2; ++b)
        op[co * 8192 + (2 * m + a) * 128 + (2 * p + b)] = fmaxf(acc[a][b][co], 0.f);
}

// ---------------------------------------------------------------------------
// Host: chunk the 169 items to fit workspace.
// Per item: bufA (x1/x3/x5, max 96*8192 floats) + bufB (x2/x4, max 128*2048).
// ---------------------------------------------------------------------------
extern "C" void kernel_launch(void* const* d_in, const int* in_sizes, int n_in,
                              void* d_out, int out_size, void* d_ws, size_t ws_size,
                              hipStream_t stream) {
  const float* f1 = (const float*)d_in[0];
  const float* f2 = (const float*)d_in[1];
  const float* w1 = (const float*)d_in[2];
  const float* w2 = (const float*)d_in[3];
  const float* w3 = (const float*)d_in[4];
  const float* w4 = (const float*)d_in[5];
  const float* wd = (const float*)d_in[6];
  const float* w5 = (const float*)d_in[7];
  float* out = (float*)d_out;

  const size_t perA = 96 * 64 * 128;   // floats: x1 (also holds x3, x5)
  const size_t perB = 128 * 32 * 64;   // floats: x2 (also holds x4)
  const size_t perItemBytes = (perA + perB) * sizeof(float);  // 4 MiB
  int G = (int)(ws_size / perItemBytes);
  if (G > NITEMS) G = NITEMS;
  if (G < 1) G = 1;

  float* A = (float*)d_ws;
  float* B = A + (size_t)G * perA;

  for (int base = 0; base < NITEMS; base += G) {
    const int cnt = (NITEMS - base < G) ? (NITEMS - base) : G;
    // x1 = relu(conv3x3(mvol))           : (96,64,128)
    k_conv1<<<dim3(32, cnt), 256, 0, stream>>>(f1, f2, w1, A, base);
    // x2 = relu(conv3x3(x1, s=2))        : (128,32,64)
    k_conv3x3<96, 128, 2, true, 64, 128><<<dim3(8, cnt), 256, 0, stream>>>(A, w2, B);
    // x3 = relu(conv3x3(x2))             : (128,32,64)
    k_conv3x3<128, 128, 1, true, 32, 64><<<dim3(8, cnt), 256, 0, stream>>>(B, w3, A);
    // x4 = relu(conv3x3(x3))             : (64,32,64)
    k_conv3x3<128, 64, 1, true, 32, 64><<<dim3(8, cnt), 256, 0, stream>>>(A, w4, B);
    // x5 = relu(deconv(x4))              : (32,64,128)
    k_deconv<<<dim3(8, cnt), 256, 0, stream>>>(B, wd, A);
    // cost = conv3x3(x5, w5), no relu    : (1,64,128) -> d_out[n]
    k_conv3x3<32, 1, 1, false, 64, 128><<<dim3(32, cnt), 256, 0, stream>>>(
        A, w5, out + (size_t)base * 8192);
  }
}

// Round 3
// 1638.903 us; speedup vs baseline: 13.7769x; 13.7769x over previous
//
#include <hip/hip_runtime.h>

#define NITEMS 169

typedef __attribute__((ext_vector_type(8))) __bf16 bf16x8;
typedef __attribute__((ext_vector_type(4))) float f32x4;
typedef __attribute__((ext_vector_type(8))) unsigned short u16x8;
typedef __attribute__((ext_vector_type(4))) unsigned short u16x4;

__device__ __forceinline__ unsigned short f2b(float x) {
  union { float f; unsigned u; } v; v.f = x;
  unsigned r = v.u + 0x7fffu + ((v.u >> 16) & 1u);
  return (unsigned short)(r >> 16);
}
__device__ __forceinline__ float b2f(unsigned short u) {
  union { unsigned u; float f; } v; v.u = ((unsigned)u) << 16;
  return v.f;
}

// Pack 3x3 conv weights [Cout][Cin][3][3] f32 -> [cout][cic][tap][32ci] bf16
__global__ void k_prep3x3(const float* __restrict__ w, unsigned short* __restrict__ wp,
                          int Cout, int Cin) {
  int i = blockIdx.x * 256 + threadIdx.x;
  if (i >= Cout * Cin * 9) return;
  int kx = i % 3, t = i / 3;
  int ky = t % 3; t /= 3;
  int cin = t % Cin, cout = t / Cin;
  int tap = ky * 3 + kx;
  wp[((cout * (Cin >> 5) + (cin >> 5)) * 9 + tap) * 32 + (cin & 31)] = f2b(w[i]);
}

// Pack deconv weights [32][64][4][4] f32 -> [ky][kx][cout][ci] bf16
__global__ void k_prepwd(const float* __restrict__ w, unsigned short* __restrict__ wp) {
  int i = blockIdx.x * 256 + threadIdx.x;
  if (i >= 32 * 64 * 16) return;
  int kx = i & 3, ky = (i >> 2) & 3, ci = (i >> 4) & 63, cout = i >> 10;
  wp[((ky * 4 + kx) * 32 + cout) * 64 + ci] = f2b(w[i]);
}

// ---------------------------------------------------------------------------
// conv1 fused with mvol: out x1 = relu(conv3x3(mvol,w1)) NHWC bf16 (64,128,96).
// LDS: X[row][cig][col][8ci], conflict-free b128 reads/writes.
// ---------------------------------------------------------------------------
__global__ __launch_bounds__(256) void k_conv1m(
    const float* __restrict__ f1, const float* __restrict__ f2,
    const unsigned short* __restrict__ wp, unsigned short* __restrict__ x1, int base) {
  const int g = blockIdx.y, item = base + g;
  const int dx = item / 13 - 6, dy = item % 13 - 6;
  const int oy = blockIdx.x;
  constexpr int WI = 130;
  __shared__ __align__(16) unsigned short X[3][4][WI][8];
  const int wid = threadIdx.x >> 6, lane = threadIdx.x & 63;
  const int lm = lane & 15, lkg = lane >> 4, lk = lkg * 8;
  const int mt0 = wid * 2;

  f32x4 acc[12];
#pragma unroll
  for (int t = 0; t < 12; ++t) acc[t] = f32x4{0.f, 0.f, 0.f, 0.f};

  for (int cic = 0; cic < 2; ++cic) {
    __syncthreads();
    for (int c = threadIdx.x; c < 3 * 4 * WI; c += 256) {
      const int cig = c & 3, t2 = c >> 2;
      const int col = t2 % WI, r = t2 / WI;
      const int iy = oy - 1 + r, ix = col - 1;
      const int sy = iy + dy, sx = ix + dx;
      u16x8 v = {0, 0, 0, 0, 0, 0, 0, 0};
      if ((unsigned)iy < 64u && (unsigned)ix < 128u &&
          (unsigned)sy < 64u && (unsigned)sx < 128u) {
        if (cic == 0) {
#pragma unroll
          for (int e = 0; e < 8; ++e)
            v[e] = f2b(f1[((cig * 8 + e) * 64 + iy) * 128 + ix]);
        } else {
#pragma unroll
          for (int e = 0; e < 8; ++e)
            v[e] = f2b(f2[((cig * 8 + e) * 64 + sy) * 128 + sx]);
        }
      }
      *(u16x8*)&X[r][cig][col][0] = v;
    }
    __syncthreads();
#pragma unroll
    for (int tap = 0; tap < 9; ++tap) {
      const int ky = tap / 3, kx = tap % 3;
      bf16x8 bf[2];
#pragma unroll
      for (int j = 0; j < 2; ++j)
        bf[j] = *(const bf16x8*)&X[ky][lkg][(mt0 + j) * 16 + lm + kx][0];
#pragma unroll
      for (int i = 0; i < 6; ++i) {
        const int cout = i * 16 + lm;
        bf16x8 af = *(const bf16x8*)&wp[((cout * 2 + cic) * 9 + tap) * 32 + lk];
#pragma unroll
        for (int j = 0; j < 2; ++j)
          acc[i * 2 + j] =
              __builtin_amdgcn_mfma_f32_16x16x32_bf16(af, bf[j], acc[i * 2 + j], 0, 0, 0);
      }
    }
  }
  unsigned short* op = x1 + (size_t)g * (8192 * 96);
#pragma unroll
  for (int i = 0; i < 6; ++i)
#pragma unroll
    for (int j = 0; j < 2; ++j) {
      const int cout0 = i * 16 + lkg * 4;
      const int m = (mt0 + j) * 16 + lm;
      u16x4 pv;
#pragma unroll
      for (int r = 0; r < 4; ++r) pv[r] = f2b(fmaxf(acc[i * 2 + j][r], 0.f));
      *(u16x4*)&op[(size_t)(oy * 128 + m) * 96 + cout0] = pv;
    }
}

// ---------------------------------------------------------------------------
// Generic 3x3 MFMA conv, NHWC bf16 in/out, fp32 accum. Block = one out row.
// STRIDE==2 uses parity-reordered LDS columns for conflict-free reads.
// ---------------------------------------------------------------------------
template <int Cin, int Cout, int H, int W, int STRIDE, bool RELU>
__global__ __launch_bounds__(256) void k_convm(
    const unsigned short* __restrict__ xin, const unsigned short* __restrict__ wp,
    unsigned short* __restrict__ xout) {
  constexpr int OH = H / STRIDE, OW = W / STRIDE;
  constexpr int WI = W + 2;
  constexpr int WIH = (WI + 1) / 2;
  constexpr int NC = Cout / 16, NM = OW / 16;
  static_assert(NC % 4 == 0, "cout tiles divisible by 4 waves");
  constexpr int WCT = NC / 4, WMT = NM;
  const int g = blockIdx.y, oy = blockIdx.x;
  const unsigned short* ip = xin + (size_t)g * Cin * H * W;
  unsigned short* op = xout + (size_t)g * Cout * OH * OW;
  __shared__ __align__(16) unsigned short X[3][4][WI][8];
  const int wid = threadIdx.x >> 6, lane = threadIdx.x & 63;
  const int lm = lane & 15, lkg = lane >> 4, lk = lkg * 8;
  const int ct0 = wid * WCT;

  f32x4 acc[WCT * WMT];
#pragma unroll
  for (int t = 0; t < WCT * WMT; ++t) acc[t] = f32x4{0.f, 0.f, 0.f, 0.f};

  for (int cic = 0; cic < Cin / 32; ++cic) {
    __syncthreads();
    for (int c = threadIdx.x; c < 3 * 4 * WI; c += 256) {
      const int cig = c & 3, t2 = c >> 2;
      const int col = t2 % WI, r = t2 / WI;
      const int iy = oy * STRIDE - 1 + r, ix = col - 1;
      const int pcol = (STRIDE == 2) ? ((col >> 1) + (col & 1) * WIH) : col;
      u16x8 v = {0, 0, 0, 0, 0, 0, 0, 0};
      if ((unsigned)iy < (unsigned)H && (unsigned)ix < (unsigned)W)
        v = *(const u16x8*)&ip[(size_t)(iy * W + ix) * Cin + cic * 32 + cig * 8];
      *(u16x8*)&X[r][cig][pcol][0] = v;
    }
    __syncthreads();
#pragma unroll
    for (int tap = 0; tap < 9; ++tap) {
      const int ky = tap / 3, kx = tap % 3;
      bf16x8 bf[WMT];
#pragma unroll
      for (int j = 0; j < WMT; ++j) {
        const int m = j * 16 + lm;
        const int colr = (STRIDE == 2) ? (m + (kx >> 1) + (kx & 1) * WIH) : (m + kx);
        bf[j] = *(const bf16x8*)&X[ky][lkg][colr][0];
      }
#pragma unroll
      for (int i = 0; i < WCT; ++i) {
        const int cout = (ct0 + i) * 16 + lm;
        bf16x8 af = *(const bf16x8*)&wp[((cout * (Cin / 32) + cic) * 9 + tap) * 32 + lk];
#pragma unroll
        for (int j = 0; j < WMT; ++j)
          acc[i * WMT + j] =
              __builtin_amdgcn_mfma_f32_16x16x32_bf16(af, bf[j], acc[i * WMT + j], 0, 0, 0);
      }
    }
  }
#pragma unroll
  for (int i = 0; i < WCT; ++i)
#pragma unroll
    for (int j = 0; j < WMT; ++j) {
      const int cout0 = (ct0 + i) * 16 + lkg * 4;
      const int m = j * 16 + lm;
      u16x4 pv;
#pragma unroll
      for (int r = 0; r < 4; ++r) {
        float f = acc[i * WMT + j][r];
        if (RELU) f = fmaxf(f, 0.f);
        pv[r] = f2b(f);
      }
      *(u16x4*)&op[(size_t)(oy * OW + m) * Cout + cout0] = pv;
    }
}

// ---------------------------------------------------------------------------
// Deconv (64->32, k=4, s=2, p=1) + relu, parity-split MFMA.
// in x4 NHWC (32,64,64); out x5 NCHW bf16 (32,64,128).
// ---------------------------------------------------------------------------
__global__ __launch_bounds__(256) void k_deconvm(
    const unsigned short* __restrict__ x4, const unsigned short* __restrict__ wp,
    unsigned short* __restrict__ x5) {
  const int g = blockIdx.y, mrow = blockIdx.x;
  const unsigned short* ip = x4 + (size_t)g * (2048 * 64);
  unsigned short* op = x5 + (size_t)g * (32 * 8192);
  constexpr int WI = 66;
  __shared__ __align__(16) unsigned short X[3][4][WI][8];
  const int wid = threadIdx.x >> 6, lane = threadIdx.x & 63;
  const int a = wid >> 1, b = wid & 1;
  const int lm = lane & 15, lkg = lane >> 4, lk = lkg * 8;
  f32x4 acc[8];
#pragma unroll
  for (int t = 0; t < 8; ++t) acc[t] = f32x4{0.f, 0.f, 0.f, 0.f};

  for (int cic = 0; cic < 2; ++cic) {
    __syncthreads();
    for (int c = threadIdx.x; c < 3 * 4 * WI; c += 256) {
      const int cig = c & 3, t2 = c >> 2;
      const int col = t2 % WI, r = t2 / WI;
      const int iy = mrow - 1 + r, ix = col - 1;
      u16x8 v = {0, 0, 0, 0, 0, 0, 0, 0};
      if ((unsigned)iy < 32u && (unsigned)ix < 64u)
        v = *(const u16x8*)&ip[(size_t)(iy * 64 + ix) * 64 + cic * 32 + cig * 8];
      *(u16x8*)&X[r][cig][col][0] = v;
    }
    __syncthreads();
#pragma unroll
    for (int u = 0; u < 2; ++u)
#pragma unroll
      for (int vv = 0; vv < 2; ++vv) {
        const int r = (a == 0) ? u : u + 1;
        const int ky = (a == 0) ? 2 * u : 2 * u + 1;
        const int s = (b == 0) ? vv : vv + 1;
        const int kx = (b == 0) ? 2 * vv : 2 * vv + 1;
        bf16x8 bf[4];
#pragma unroll
        for (int j = 0; j < 4; ++j)
          bf[j] = *(const bf16x8*)&X[r][lkg][j * 16 + lm + s][0];
#pragma unroll
        for (int i = 0; i < 2; ++i) {
          const int cout = i * 16 + lm;
          bf16x8 af = *(const bf16x8*)&wp[((ky * 4 + kx) * 32 + cout) * 64 + cic * 32 + lk];
#pragma unroll
          for (int j = 0; j < 4; ++j)
            acc[i * 4 + j] =
                __builtin_amdgcn_mfma_f32_16x16x32_bf16(af, bf[j], acc[i * 4 + j], 0, 0, 0);
        }
      }
  }
#pragma unroll
  for (int i = 0; i < 2; ++i)
#pragma unroll
    for (int j = 0; j < 4; ++j) {
      const int cout0 = i * 16 + lkg * 4;
      const int p = j * 16 + lm;
      const int orow = 2 * mrow + a, ocol = 2 * p + b;
#pragma unroll
      for (int r2 = 0; r2 < 4; ++r2)
        op[(cout0 + r2) * 8192 + orow * 128 + ocol] = f2b(fmaxf(acc[i * 4 + j][r2], 0.f));
    }
}

// ---------------------------------------------------------------------------
// conv5 (32->1): scalar, transposed padded LDS (conflict-free). in x5 NCHW.
// Block = 2 out rows. fp32 out.
// ---------------------------------------------------------------------------
__global__ __launch_bounds__(256) void k_conv5m(
    const unsigned short* __restrict__ x5, const float* __restrict__ w5,
    float* __restrict__ out) {
  const int g = blockIdx.y, yb = blockIdx.x;
  const unsigned short* ip = x5 + (size_t)g * (32 * 8192);
  __shared__ unsigned short X[32][4][132];
  for (int e = threadIdx.x; e < 32 * 4 * 130; e += 256) {
    const int col = e % 130, t2 = e / 130;
    const int rr = t2 & 3, ci = t2 >> 2;
    const int iy = 2 * yb - 1 + rr, ix = col - 1;
    unsigned short v = 0;
    if ((unsigned)iy < 64u && (unsigned)ix < 128u)
      v = ip[(ci * 64 + iy) * 128 + ix];
    X[ci][rr][col] = v;
  }
  __syncthreads();
  const int r = threadIdx.x >> 7, col = threadIdx.x & 127;
  float s = 0.f;
#pragma unroll 1
  for (int ci = 0; ci < 32; ++ci) {
#pragma unroll
    for (int t = 0; t < 9; ++t)
      s += b2f(X[ci][r + t / 3][col + t % 3]) * w5[ci * 9 + t];
  }
  out[(size_t)g * 8192 + (size_t)(2 * yb + r) * 128 + col] = s;
}

// ---------------------------------------------------------------------------
// Host: weights packed once; items chunked (A=1.5MiB + B=0.5MiB per item)
// to fit ws (~256 MiB -> G~127, 2 chunks).
// ---------------------------------------------------------------------------
extern "C" void kernel_launch(void* const* d_in, const int* in_sizes, int n_in,
                              void* d_out, int out_size, void* d_ws, size_t ws_size,
                              hipStream_t stream) {
  const float* f1 = (const float*)d_in[0];
  const float* f2 = (const float*)d_in[1];
  const float* w1 = (const float*)d_in[2];
  const float* w2 = (const float*)d_in[3];
  const float* w3 = (const float*)d_in[4];
  const float* w4 = (const float*)d_in[5];
  const float* wd = (const float*)d_in[6];
  const float* w5 = (const float*)d_in[7];
  float* out = (float*)d_out;

  size_t off = 0;
  auto alloc = [&](size_t elems) {
    unsigned short* p = (unsigned short*)((char*)d_ws + off);
    off += ((elems * 2 + 255) / 256) * 256;
    return p;
  };
  unsigned short* w1p = alloc(96 * 2 * 9 * 32);
  unsigned short* w2p = alloc(128 * 3 * 9 * 32);
  unsigned short* w3p = alloc(128 * 4 * 9 * 32);
  unsigned short* w4p = alloc(64 * 4 * 9 * 32);
  unsigned short* wdp = alloc(16 * 32 * 64);
  const size_t wend = off;

  const size_t perA = (size_t)96 * 8192 * 2;   // bytes: x1 (also x3, x5)
  const size_t perB = (size_t)128 * 2048 * 2;  // bytes: x2 (also x4)
  int G = (int)((ws_size - wend) / (perA + perB));
  if (G > NITEMS) G = NITEMS;
  if (G < 1) G = 1;
  unsigned short* A = (unsigned short*)((char*)d_ws + wend);
  unsigned short* B = (unsigned short*)((char*)d_ws + wend + (size_t)G * perA);

  k_prep3x3<<<(96 * 64 * 9 + 255) / 256, 256, 0, stream>>>(w1, w1p, 96, 64);
  k_prep3x3<<<(128 * 96 * 9 + 255) / 256, 256, 0, stream>>>(w2, w2p, 128, 96);
  k_prep3x3<<<(128 * 128 * 9 + 255) / 256, 256, 0, stream>>>(w3, w3p, 128, 128);
  k_prep3x3<<<(64 * 128 * 9 + 255) / 256, 256, 0, stream>>>(w4, w4p, 64, 128);
  k_prepwd<<<(32 * 64 * 16 + 255) / 256, 256, 0, stream>>>(wd, wdp);

  for (int base = 0; base < NITEMS; base += G) {
    const int cnt = (NITEMS - base < G) ? (NITEMS - base) : G;
    k_conv1m<<<dim3(64, cnt), 256, 0, stream>>>(f1, f2, w1p, A, base);
    k_convm<96, 128, 64, 128, 2, true><<<dim3(32, cnt), 256, 0, stream>>>(A, w2p, B);
    k_convm<128, 128, 32, 64, 1, true><<<dim3(32, cnt), 256, 0, stream>>>(B, w3p, A);
    k_convm<128, 64, 32, 64, 1, true><<<dim3(32, cnt), 256, 0, stream>>>(A, w4p, B);
    k_deconvm<<<dim3(32, cnt), 256, 0, stream>>>(B, wdp, A);
    k_conv5m<<<dim3(32, cnt), 256, 0, stream>>>(A, w5, out + (size_t)base * 8192);
  }
}

// Round 4
// 797.496 us; speedup vs baseline: 28.3124x; 2.0551x over previous
//
#include <hip/hip_runtime.h>

#define NITEMS 169

typedef __attribute__((ext_vector_type(8))) __bf16 bf16x8;
typedef __attribute__((ext_vector_type(4))) float f32x4;
typedef __attribute__((ext_vector_type(8))) unsigned short u16x8;
typedef __attribute__((ext_vector_type(4))) unsigned short u16x4;

__device__ __forceinline__ unsigned short f2b(float x) {
  union { float f; unsigned u; } v; v.f = x;
  unsigned r = v.u + 0x7fffu + ((v.u >> 16) & 1u);
  return (unsigned short)(r >> 16);
}
__device__ __forceinline__ float b2f(unsigned short u) {
  union { unsigned u; float f; } v; v.u = ((unsigned)u) << 16;
  return v.f;
}

// f32 NCHW (32,64,128) -> bf16 NHWC (64,128,32)
__global__ __launch_bounds__(256) void k_prepf(const float* __restrict__ f,
                                               unsigned short* __restrict__ fb) {
  const int pix = blockIdx.x * 256 + threadIdx.x;  // 0..8191
  const int y = pix >> 7, x = pix & 127;
#pragma unroll
  for (int c = 0; c < 32; ++c)
    fb[(size_t)pix * 32 + c] = f2b(f[(c * 64 + y) * 128 + x]);
}

// Pack 3x3 conv weights [Cout][Cin][3][3] f32 -> [cic][tap][cout][32ci] bf16
__global__ void k_prep3x3(const float* __restrict__ w, unsigned short* __restrict__ wp,
                          int Cout, int Cin) {
  int i = blockIdx.x * 256 + threadIdx.x;
  if (i >= Cout * Cin * 9) return;
  int kx = i % 3, t = i / 3;
  int ky = t % 3; t /= 3;
  int cin = t % Cin, cout = t / Cin;
  int tap = ky * 3 + kx;
  wp[(((cin >> 5) * 9 + tap) * Cout + cout) * 32 + (cin & 31)] = f2b(w[i]);
}

// Pack deconv weights [32][64][4][4] f32 -> [cic][ky][kx][cout][32ci] bf16
__global__ void k_prepwd(const float* __restrict__ w, unsigned short* __restrict__ wp) {
  int i = blockIdx.x * 256 + threadIdx.x;
  if (i >= 32 * 64 * 16) return;
  int kx = i & 3, ky = (i >> 2) & 3, ci = (i >> 4) & 63, cout = i >> 10;
  wp[(((((ci >> 5) * 4 + ky) * 4 + kx) * 32) + cout) * 32 + (ci & 31)] = f2b(w[i]);
}

// ---------------------------------------------------------------------------
// conv1 fused with mvol; bf16 NHWC inputs; 2 output rows per block.
// out x1 = relu(conv3x3(mvol,w1)) NHWC bf16 (64,128,96).
// ---------------------------------------------------------------------------
__global__ __launch_bounds__(256) void k_conv1m(
    const unsigned short* __restrict__ f1b, const unsigned short* __restrict__ f2bp,
    const unsigned short* __restrict__ wp, unsigned short* __restrict__ x1, int base) {
  const int g = blockIdx.y, item = base + g;
  const int dx = item / 13 - 6, dy = item % 13 - 6;
  const int oy0 = blockIdx.x * 2;
  constexpr int WI = 130;
  __shared__ __align__(16) unsigned short X[4][4][WI][8];
  const int wid = threadIdx.x >> 6, lane = threadIdx.x & 63;
  const int lm = lane & 15, lkg = lane >> 4, lk = lkg * 8;

  f32x4 acc[24];
#pragma unroll
  for (int t = 0; t < 24; ++t) acc[t] = f32x4{0.f, 0.f, 0.f, 0.f};

  for (int cic = 0; cic < 2; ++cic) {
    __syncthreads();
    const unsigned short* src = cic ? f2bp : f1b;
    for (int c = threadIdx.x; c < 4 * 4 * WI; c += 256) {
      const int cig = c & 3, t2 = c >> 2;
      const int col = t2 % WI, r = t2 / WI;
      const int iy = oy0 - 1 + r, ix = col - 1;
      const int sy = iy + dy, sx = ix + dx;
      u16x8 v = {0, 0, 0, 0, 0, 0, 0, 0};
      if ((unsigned)iy < 64u && (unsigned)ix < 128u &&
          (unsigned)sy < 64u && (unsigned)sx < 128u) {
        const int py = cic ? sy : iy, px = cic ? sx : ix;
        v = *(const u16x8*)&src[(size_t)(py * 128 + px) * 32 + cig * 8];
      }
      *(u16x8*)&X[r][cig][col][0] = v;
    }
    __syncthreads();
#pragma unroll
    for (int tap = 0; tap < 9; ++tap) {
      const int ky = tap / 3, kx = tap % 3;
      bf16x8 bf[4];
#pragma unroll
      for (int j = 0; j < 4; ++j) {
        const int mt = wid * 4 + j, rw = mt >> 3, mtx = mt & 7;
        bf[j] = *(const bf16x8*)&X[rw + ky][lkg][mtx * 16 + lm + kx][0];
      }
#pragma unroll
      for (int i = 0; i < 6; ++i) {
        bf16x8 af = *(const bf16x8*)&wp[((cic * 9 + tap) * 96 + i * 16 + lm) * 32 + lk];
#pragma unroll
        for (int j = 0; j < 4; ++j)
          acc[i * 4 + j] =
              __builtin_amdgcn_mfma_f32_16x16x32_bf16(af, bf[j], acc[i * 4 + j], 0, 0, 0);
      }
    }
  }
  unsigned short* op = x1 + (size_t)g * (8192 * 96);
#pragma unroll
  for (int i = 0; i < 6; ++i)
#pragma unroll
    for (int j = 0; j < 4; ++j) {
      const int mt = wid * 4 + j, rw = mt >> 3, mtx = mt & 7;
      const int cout0 = i * 16 + lkg * 4;
      const int m = mtx * 16 + lm;
      u16x4 pv;
#pragma unroll
      for (int r = 0; r < 4; ++r) pv[r] = f2b(fmaxf(acc[i * 4 + j][r], 0.f));
      *(u16x4*)&op[(size_t)((oy0 + rw) * 128 + m) * 96 + cout0] = pv;
    }
}

// ---------------------------------------------------------------------------
// Generic 3x3 MFMA conv, NHWC bf16 in/out, fp32 accum. Block = one out row.
// STRIDE==2 uses parity-reordered LDS columns for conflict-free reads.
// ---------------------------------------------------------------------------
template <int Cin, int Cout, int H, int W, int STRIDE, bool RELU>
__global__ __launch_bounds__(256) void k_convm(
    const unsigned short* __restrict__ xin, const unsigned short* __restrict__ wp,
    unsigned short* __restrict__ xout) {
  constexpr int OH = H / STRIDE, OW = W / STRIDE;
  constexpr int WI = W + 2;
  constexpr int WIH = (WI + 1) / 2;
  constexpr int NC = Cout / 16, NM = OW / 16;
  static_assert(NC % 4 == 0, "cout tiles divisible by 4 waves");
  constexpr int WCT = NC / 4, WMT = NM;
  const int g = blockIdx.y, oy = blockIdx.x;
  const unsigned short* ip = xin + (size_t)g * Cin * H * W;
  unsigned short* op = xout + (size_t)g * Cout * OH * OW;
  __shared__ __align__(16) unsigned short X[3][4][WI][8];
  const int wid = threadIdx.x >> 6, lane = threadIdx.x & 63;
  const int lm = lane & 15, lkg = lane >> 4, lk = lkg * 8;
  const int ct0 = wid * WCT;

  f32x4 acc[WCT * WMT];
#pragma unroll
  for (int t = 0; t < WCT * WMT; ++t) acc[t] = f32x4{0.f, 0.f, 0.f, 0.f};

  for (int cic = 0; cic < Cin / 32; ++cic) {
    __syncthreads();
    for (int c = threadIdx.x; c < 3 * 4 * WI; c += 256) {
      const int cig = c & 3, t2 = c >> 2;
      const int col = t2 % WI, r = t2 / WI;
      const int iy = oy * STRIDE - 1 + r, ix = col - 1;
      const int pcol = (STRIDE == 2) ? ((col >> 1) + (col & 1) * WIH) : col;
      u16x8 v = {0, 0, 0, 0, 0, 0, 0, 0};
      if ((unsigned)iy < (unsigned)H && (unsigned)ix < (unsigned)W)
        v = *(const u16x8*)&ip[(size_t)(iy * W + ix) * Cin + cic * 32 + cig * 8];
      *(u16x8*)&X[r][cig][pcol][0] = v;
    }
    __syncthreads();
#pragma unroll
    for (int tap = 0; tap < 9; ++tap) {
      const int ky = tap / 3, kx = tap % 3;
      bf16x8 bf[WMT];
#pragma unroll
      for (int j = 0; j < WMT; ++j) {
        const int m = j * 16 + lm;
        const int colr = (STRIDE == 2) ? (m + (kx >> 1) + (kx & 1) * WIH) : (m + kx);
        bf[j] = *(const bf16x8*)&X[ky][lkg][colr][0];
      }
#pragma unroll
      for (int i = 0; i < WCT; ++i) {
        const int cout = (ct0 + i) * 16 + lm;
        bf16x8 af = *(const bf16x8*)&wp[((cic * 9 + tap) * Cout + cout) * 32 + lk];
#pragma unroll
        for (int j = 0; j < WMT; ++j)
          acc[i * WMT + j] =
              __builtin_amdgcn_mfma_f32_16x16x32_bf16(af, bf[j], acc[i * WMT + j], 0, 0, 0);
      }
    }
  }
#pragma unroll
  for (int i = 0; i < WCT; ++i)
#pragma unroll
    for (int j = 0; j < WMT; ++j) {
      const int cout0 = (ct0 + i) * 16 + lkg * 4;
      const int m = j * 16 + lm;
      u16x4 pv;
#pragma unroll
      for (int r = 0; r < 4; ++r) {
        float f = acc[i * WMT + j][r];
        if (RELU) f = fmaxf(f, 0.f);
        pv[r] = f2b(f);
      }
      *(u16x4*)&op[(size_t)(oy * OW + m) * Cout + cout0] = pv;
    }
}

// ---------------------------------------------------------------------------
// Deconv (64->32, k=4, s=2, p=1) + relu, parity-split MFMA.
// in x4 NHWC (32,64,64); out x5 NHWC bf16 (64,128,32).
// ---------------------------------------------------------------------------
__global__ __launch_bounds__(256) void k_deconvm(
    const unsigned short* __restrict__ x4, const unsigned short* __restrict__ wp,
    unsigned short* __restrict__ x5) {
  const int g = blockIdx.y, mrow = blockIdx.x;
  const unsigned short* ip = x4 + (size_t)g * (2048 * 64);
  unsigned short* op = x5 + (size_t)g * (8192 * 32);
  constexpr int WI = 66;
  __shared__ __align__(16) unsigned short X[3][4][WI][8];
  const int wid = threadIdx.x >> 6, lane = threadIdx.x & 63;
  const int a = wid >> 1, b = wid & 1;
  const int lm = lane & 15, lkg = lane >> 4, lk = lkg * 8;
  f32x4 acc[8];
#pragma unroll
  for (int t = 0; t < 8; ++t) acc[t] = f32x4{0.f, 0.f, 0.f, 0.f};

  for (int cic = 0; cic < 2; ++cic) {
    __syncthreads();
    for (int c = threadIdx.x; c < 3 * 4 * WI; c += 256) {
      const int cig = c & 3, t2 = c >> 2;
      const int col = t2 % WI, r = t2 / WI;
      const int iy = mrow - 1 + r, ix = col - 1;
      u16x8 v = {0, 0, 0, 0, 0, 0, 0, 0};
      if ((unsigned)iy < 32u && (unsigned)ix < 64u)
        v = *(const u16x8*)&ip[(size_t)(iy * 64 + ix) * 64 + cic * 32 + cig * 8];
      *(u16x8*)&X[r][cig][col][0] = v;
    }
    __syncthreads();
#pragma unroll
    for (int u = 0; u < 2; ++u)
#pragma unroll
      for (int vv = 0; vv < 2; ++vv) {
        const int r = (a == 0) ? u : u + 1;
        const int ky = (a == 0) ? 2 * u : 2 * u + 1;
        const int s = (b == 0) ? vv : vv + 1;
        const int kx = (b == 0) ? 2 * vv : 2 * vv + 1;
        bf16x8 bf[4];
#pragma unroll
        for (int j = 0; j < 4; ++j)
          bf[j] = *(const bf16x8*)&X[r][lkg][j * 16 + lm + s][0];
#pragma unroll
        for (int i = 0; i < 2; ++i) {
          bf16x8 af =
              *(const bf16x8*)&wp[((((cic * 4 + ky) * 4 + kx) * 32) + i * 16 + lm) * 32 + lk];
#pragma unroll
          for (int j = 0; j < 4; ++j)
            acc[i * 4 + j] =
                __builtin_amdgcn_mfma_f32_16x16x32_bf16(af, bf[j], acc[i * 4 + j], 0, 0, 0);
        }
      }
  }
#pragma unroll
  for (int i = 0; i < 2; ++i)
#pragma unroll
    for (int j = 0; j < 4; ++j) {
      const int cout0 = i * 16 + lkg * 4;
      const int p = j * 16 + lm;
      const int orow = 2 * mrow + a, ocol = 2 * p + b;
      u16x4 pv;
#pragma unroll
      for (int r2 = 0; r2 < 4; ++r2) pv[r2] = f2b(fmaxf(acc[i * 4 + j][r2], 0.f));
      *(u16x4*)&op[(size_t)(orow * 128 + ocol) * 32 + cout0] = pv;
    }
}

// ---------------------------------------------------------------------------
// conv5 (32->1, 3x3): direct from L2, NHWC input, fp32 out. Thread per pixel.
// ---------------------------------------------------------------------------
__global__ __launch_bounds__(256) void k_conv5m(
    const unsigned short* __restrict__ x5, const float* __restrict__ w5,
    float* __restrict__ out) {
  const int g = blockIdx.y;
  const int pix = blockIdx.x * 256 + threadIdx.x;
  const int y = pix >> 7, x = pix & 127;
  const unsigned short* ip = x5 + (size_t)g * (8192 * 32);
  float s = 0.f;
#pragma unroll
  for (int t = 0; t < 9; ++t) {
    const int yy = y - 1 + t / 3, xx = x - 1 + t % 3;
    if ((unsigned)yy < 64u && (unsigned)xx < 128u) {
#pragma unroll
      for (int cg = 0; cg < 4; ++cg) {
        u16x8 v = *(const u16x8*)&ip[(size_t)(yy * 128 + xx) * 32 + cg * 8];
#pragma unroll
        for (int e = 0; e < 8; ++e) s += b2f(v[e]) * w5[(cg * 8 + e) * 9 + t];
      }
    }
  }
  out[(size_t)g * 8192 + pix] = s;
}

// ---------------------------------------------------------------------------
extern "C" void kernel_launch(void* const* d_in, const int* in_sizes, int n_in,
                              void* d_out, int out_size, void* d_ws, size_t ws_size,
                              hipStream_t stream) {
  const float* f1 = (const float*)d_in[0];
  const float* f2 = (const float*)d_in[1];
  const float* w1 = (const float*)d_in[2];
  const float* w2 = (const float*)d_in[3];
  const float* w3 = (const float*)d_in[4];
  const float* w4 = (const float*)d_in[5];
  const float* wd = (const float*)d_in[6];
  const float* w5 = (const float*)d_in[7];
  float* out = (float*)d_out;

  size_t off = 0;
  auto alloc = [&](size_t elems) {
    unsigned short* p = (unsigned short*)((char*)d_ws + off);
    off += ((elems * 2 + 255) / 256) * 256;
    return p;
  };
  unsigned short* f1b = alloc(64 * 128 * 32);
  unsigned short* f2bp = alloc(64 * 128 * 32);
  unsigned short* w1p = alloc(2 * 9 * 96 * 32);
  unsigned short* w2p = alloc(3 * 9 * 128 * 32);
  unsigned short* w3p = alloc(4 * 9 * 128 * 32);
  unsigned short* w4p = alloc(4 * 9 * 64 * 32);
  unsigned short* wdp = alloc(2 * 16 * 32 * 32);
  const size_t wend = off;

  const size_t perA = (size_t)96 * 8192 * 2;   // bytes: x1 (also x3, x5)
  const size_t perB = (size_t)128 * 2048 * 2;  // bytes: x2 (also x4)
  int G = (int)((ws_size - wend) / (perA + perB));
  if (G > NITEMS) G = NITEMS;
  if (G < 1) G = 1;
  unsigned short* A = (unsigned short*)((char*)d_ws + wend);
  unsigned short* B = (unsigned short*)((char*)d_ws + wend + (size_t)G * perA);

  k_prepf<<<32, 256, 0, stream>>>(f1, f1b);
  k_prepf<<<32, 256, 0, stream>>>(f2, f2bp);
  k_prep3x3<<<(96 * 64 * 9 + 255) / 256, 256, 0, stream>>>(w1, w1p, 96, 64);
  k_prep3x3<<<(128 * 96 * 9 + 255) / 256, 256, 0, stream>>>(w2, w2p, 128, 96);
  k_prep3x3<<<(128 * 128 * 9 + 255) / 256, 256, 0, stream>>>(w3, w3p, 128, 128);
  k_prep3x3<<<(64 * 128 * 9 + 255) / 256, 256, 0, stream>>>(w4, w4p, 64, 128);
  k_prepwd<<<(32 * 64 * 16 + 255) / 256, 256, 0, stream>>>(wd, wdp);

  for (int base = 0; base < NITEMS; base += G) {
    const int cnt = (NITEMS - base < G) ? (NITEMS - base) : G;
    k_conv1m<<<dim3(32, cnt), 256, 0, stream>>>(f1b, f2bp, w1p, A, base);
    k_convm<96, 128, 64, 128, 2, true><<<dim3(32, cnt), 256, 0, stream>>>(A, w2p, B);
    k_convm<128, 128, 32, 64, 1, true><<<dim3(32, cnt), 256, 0, stream>>>(B, w3p, A);
    k_convm<128, 64, 32, 64, 1, true><<<dim3(32, cnt), 256, 0, stream>>>(A, w4p, B);
    k_deconvm<<<dim3(32, cnt), 256, 0, stream>>>(B, wdp, A);
    k_conv5m<<<dim3(32, cnt), 256, 0, stream>>>(A, w5, out + (size_t)base * 8192);
  }
}